// Round 5
// baseline (131.322 us; speedup 1.0000x reference)
//
#include <hip/hip_runtime.h>

#define HH 512
#define WW 512
#define RSTRIP 16          // ncc output rows per 128-thread strip
#define NCC_BLOCKS 1024    // 2048 strips, 2 per 256-thread block
#define REG_BLOCKS 1024    // 2048 strips of 32 rows, 2 per block

// 12 consecutive floats of one row: cols 4tt-4 .. 4tt+7 (zeros outside image).
__device__ __forceinline__ void ld12(const float* __restrict__ row, int tt,
                                     float v[12]) {
    const float4* p = reinterpret_cast<const float4*>(row) + tt;
    float4 a = (tt > 0)   ? p[-1] : make_float4(0.f, 0.f, 0.f, 0.f);
    float4 b = p[0];
    float4 c = (tt < 127) ? p[1]  : make_float4(0.f, 0.f, 0.f, 0.f);
    v[0] = a.x; v[1] = a.y; v[2]  = a.z; v[3]  = a.w;
    v[4] = b.x; v[5] = b.y; v[6]  = b.z; v[7]  = b.w;
    v[8] = c.x; v[9] = c.y; v[10] = c.z; v[11] = c.w;
}

// 9-wide sliding fold of d[0..11] into bx[0..3] (outputs cols 4tt..4tt+3).
__device__ __forceinline__ void win_acc(const float d[12], float* bx) {
    float s = ((d[0] + d[1]) + (d[2] + d[3])) +
              ((d[4] + d[5]) + (d[6] + d[7])) + d[8];
    bx[0] += s;
    s += d[9]  - d[0]; bx[1] += s;
    s += d[10] - d[1]; bx[2] += s;
    s += d[11] - d[2]; bx[3] += s;
}

// Row-step: add lead row (HASL), remove trail row (HAST), diff at product level.
// All loads are issued as one independent cluster before any compute.
template<bool HASL, bool HAST>
__device__ __forceinline__ void upd(const float* __restrict__ Il,
                                    const float* __restrict__ Jl,
                                    const float* __restrict__ It,
                                    const float* __restrict__ Jt,
                                    int tt, float B[5][4]) {
    float li[12], lj[12], ti[12], tj[12], d[12];
    if (HASL) { ld12(Il, tt, li); ld12(Jl, tt, lj); }
    if (HAST) { ld12(It, tt, ti); ld12(Jt, tt, tj); }

#pragma unroll
    for (int c = 0; c < 12; ++c)
        d[c] = HASL ? (HAST ? li[c] - ti[c] : li[c]) : -ti[c];
    win_acc(d, B[0]);
#pragma unroll
    for (int c = 0; c < 12; ++c)
        d[c] = HASL ? (HAST ? lj[c] - tj[c] : lj[c]) : -tj[c];
    win_acc(d, B[1]);
#pragma unroll
    for (int c = 0; c < 12; ++c)
        d[c] = HASL ? (HAST ? fmaf(li[c], li[c], -(ti[c] * ti[c]))
                            : li[c] * li[c])
                    : -(ti[c] * ti[c]);
    win_acc(d, B[2]);
#pragma unroll
    for (int c = 0; c < 12; ++c)
        d[c] = HASL ? (HAST ? fmaf(lj[c], lj[c], -(tj[c] * tj[c]))
                            : lj[c] * lj[c])
                    : -(tj[c] * tj[c]);
    win_acc(d, B[3]);
#pragma unroll
    for (int c = 0; c < 12; ++c)
        d[c] = HASL ? (HAST ? fmaf(li[c], lj[c], -(ti[c] * tj[c]))
                            : li[c] * lj[c])
                    : -(ti[c] * tj[c]);
    win_acc(d, B[4]);
}

__device__ __forceinline__ float cc_row(const float B[5][4]) {
    const float inv81 = 1.f / 81.f;
    float a = 0.f;
#pragma unroll
    for (int o = 0; o < 4; ++o) {
        float IS = B[0][o], JS = B[1][o];
        float I2 = B[2][o], J2 = B[3][o], IJ = B[4][o];
        float cross = fmaf(-(IS * JS), inv81, IJ);
        float Iv = fmaf(-(IS * IS), inv81, I2);
        float Jv = fmaf(-(JS * JS), inv81, J2);
        float denom = fmaf(Iv, Jv, 1e-5f);
        a = fmaf(cross * cross, __builtin_amdgcn_rcpf(denom), a);
    }
    return a;
}

__device__ void ncc_body(int sbid, const float* __restrict__ I,
                         const float* __restrict__ J, float* __restrict__ ws,
                         float* sh) {
    const int T = threadIdx.x;
    const int tt = T & 127;                    // cols 4tt..4tt+3
    const int strip = (sbid << 1) | (T >> 7);  // 0..2047
    const int b = strip >> 5;                  // 32 strips per image
    const int r0 = (strip & 31) << 4;

    const float* Ib = I + (size_t)b * (HH * WW);
    const float* Jb = J + (size_t)b * (HH * WW);

    float B[5][4];
#pragma unroll
    for (int k = 0; k < 5; ++k)
#pragma unroll
        for (int o = 0; o < 4; ++o) B[k][o] = 0.f;

    // warm-up: rows r0-4 .. r0+4 (uniform skip above image top)
    for (int j = r0 - 4; j <= r0 + 4; ++j) {
        if (j >= 0)
            upd<true, false>(Ib + (size_t)j * WW, Jb + (size_t)j * WW,
                             Ib, Jb, tt, B);
    }

    float acc = 0.f;
    for (int h = 0;; ++h) {
        acc += cc_row(B);                      // output row r0+h
        if (h == RSTRIP - 1) break;
        const int jl = r0 + h + 5;             // row entering the window
        const int jt = r0 + h - 4;             // row leaving the window
        const float* IlP = Ib + (size_t)jl * WW;
        const float* JlP = Jb + (size_t)jl * WW;
        const float* ItP = Ib + (size_t)jt * WW;
        const float* JtP = Jb + (size_t)jt * WW;
        if (jl < HH) {                         // wave-uniform branches
            if (jt >= 0) upd<true, true>(IlP, JlP, ItP, JtP, tt, B);
            else         upd<true, false>(IlP, JlP, Ib, Jb, tt, B);
        } else if (jt >= 0) {
            upd<false, true>(Ib, Jb, ItP, JtP, tt, B);
        }
    }

#pragma unroll
    for (int off = 32; off; off >>= 1) acc += __shfl_down(acc, off);
    if ((T & 63) == 0) sh[T >> 6] = acc;
    __syncthreads();
    if (T == 0) atomicAdd(&ws[0], sh[0] + sh[1] + sh[2] + sh[3]);
}

__device__ void reg_body(int sbid, const float* __restrict__ P,
                         float* __restrict__ ws, float* sh) {
    const int T = threadIdx.x;
    const int c4 = T & 127;                    // 128 float4s = one row
    const int strip = (sbid << 1) | (T >> 7);  // 0..2047 over 65536 rows
    const size_t row0 = (size_t)strip << 5;    // *32 rows per strip
    const bool slast = ((strip & 15) == 15);   // strip ends at image row 511
    const float* rp = P + row0 * WW + (c4 << 2);

    float sdx = 0.f, sdy = 0.f;
    float4 cur = *reinterpret_cast<const float4*>(rp);
#pragma unroll 8
    for (int i = 0; i < 32; ++i) {
        float d0 = cur.y - cur.x, d1 = cur.z - cur.y, d2 = cur.w - cur.z;
        sdx += d0 * d0 + d1 * d1 + d2 * d2;
        if (c4 < 127) {                        // neighbor's first elem (cache hit)
            float nx = rp[(size_t)i * WW + 4];
            float d3 = nx - cur.w;
            sdx += d3 * d3;
        }
        if (i < 31) {
            float4 nr = *reinterpret_cast<const float4*>(rp + (size_t)(i + 1) * WW);
            float e0 = nr.x - cur.x, e1 = nr.y - cur.y;
            float e2 = nr.z - cur.z, e3 = nr.w - cur.w;
            sdy += e0 * e0 + e1 * e1 + e2 * e2 + e3 * e3;
            cur = nr;
        } else if (!slast) {                   // dy last strip row -> next strip
            float4 nr = *reinterpret_cast<const float4*>(rp + (size_t)32 * WW);
            float e0 = nr.x - cur.x, e1 = nr.y - cur.y;
            float e2 = nr.z - cur.z, e3 = nr.w - cur.w;
            sdy += e0 * e0 + e1 * e1 + e2 * e2 + e3 * e3;
        }
    }

#pragma unroll
    for (int off = 32; off; off >>= 1) {
        sdx += __shfl_down(sdx, off);
        sdy += __shfl_down(sdy, off);
    }
    if ((T & 63) == 0) { sh[T >> 6] = sdx; sh[4 + (T >> 6)] = sdy; }
    __syncthreads();
    if (T == 0) {
        atomicAdd(&ws[1], sh[0] + sh[1] + sh[2] + sh[3]);
        atomicAdd(&ws[2], sh[4] + sh[5] + sh[6] + sh[7]);
    }
}

// Heterogeneous grid: odd blocks = NCC (VALU), even = reg (HBM stream).
// 2048 blocks = 8 blocks/CU = full 32-wave/CU occupancy (VGPR permitting).
__global__ __launch_bounds__(256, 4) void fused_kernel(
        const float* __restrict__ I, const float* __restrict__ J,
        const float* __restrict__ P, float* __restrict__ ws) {
    __shared__ float sh[8];
    const int bid = blockIdx.x;
    if (bid & 1) ncc_body(bid >> 1, I, J, ws, sh);
    else         reg_body(bid >> 1, P, ws, sh);
}

__global__ void finalize_kernel(const float* __restrict__ ws,
                                float* __restrict__ out) {
    float cc_sum = ws[0], dx_sum = ws[1], dy_sum = ws[2];
    float loss_sim = -(cc_sum / 16777216.f);   // 64*512*512
    float mdx = dx_sum / 33488896.f;           // 64*2*512*511
    float mdy = dy_sum / 33488896.f;           // 64*2*511*512
    float loss_reg = (mdx + mdy) * 0.5f * 0.1f;
    out[0] = loss_sim;
    out[1] = loss_reg;
    out[2] = loss_sim + loss_reg;
}

extern "C" void kernel_launch(void* const* d_in, const int* in_sizes, int n_in,
                              void* d_out, int out_size, void* d_ws, size_t ws_size,
                              hipStream_t stream) {
    const float* I = (const float*)d_in[0];   // target_proj
    const float* J = (const float*)d_in[1];   // warped_moving
    const float* P = (const float*)d_in[2];   // phi
    float* out = (float*)d_out;
    float* ws = (float*)d_ws;

    hipMemsetAsync(d_ws, 0, 3 * sizeof(float), stream);
    fused_kernel<<<NCC_BLOCKS + REG_BLOCKS, 256, 0, stream>>>(I, J, P, ws);
    finalize_kernel<<<1, 1, 0, stream>>>(ws, out);
}

// Round 6
// 119.157 us; speedup vs baseline: 1.1021x; 1.1021x over previous
//
#include <hip/hip_runtime.h>

#define HH 512
#define WW 512
#define RSTRIP 64          // output rows per block-strip (512 ncc blocks)
#define DRING 16           // LDS ring depth (rows), power of 2

#define WAITVM(n) asm volatile("s_waitcnt vmcnt(" #n ")" ::: "memory")

// Async global->LDS, 16B per lane. LDS dest = wave-uniform base + lane*16.
__device__ __forceinline__ void gload16(const float* g, float* l) {
    __builtin_amdgcn_global_load_lds(
        (const __attribute__((address_space(1))) void*)g,
        (__attribute__((address_space(3))) void*)l, 16, 0, 0);
}

// Read 12 floats (cols 4t-4 .. 4t+7) of one ring row from LDS; zeros outside.
__device__ __forceinline__ void lds12(const float* __restrict__ rowp, int t,
                                      float v[12]) {
    const float4* p = reinterpret_cast<const float4*>(rowp) + t;
    float4 a = (t > 0)   ? p[-1] : make_float4(0.f, 0.f, 0.f, 0.f);
    float4 b = p[0];
    float4 c = (t < 127) ? p[1]  : make_float4(0.f, 0.f, 0.f, 0.f);
    v[0] = a.x; v[1] = a.y; v[2]  = a.z; v[3]  = a.w;
    v[4] = b.x; v[5] = b.y; v[6]  = b.z; v[7]  = b.w;
    v[8] = c.x; v[9] = c.y; v[10] = c.z; v[11] = c.w;
}

// 9-wide sliding fold of d[0..11] into bx[0..3].
__device__ __forceinline__ void win_acc(const float d[12], float* bx) {
    float s = ((d[0] + d[1]) + (d[2] + d[3])) +
              ((d[4] + d[5]) + (d[6] + d[7])) + d[8];
    bx[0] += s;
    s += d[9]  - d[0]; bx[1] += s;
    s += d[10] - d[1]; bx[2] += s;
    s += d[11] - d[2]; bx[3] += s;
}

// Warm-up: add one row's products into the boxes.
__device__ __forceinline__ void acc_lead(const float li[12], const float lj[12],
                                         float B[5][4]) {
    float d[12];
    win_acc(li, B[0]);
    win_acc(lj, B[1]);
#pragma unroll
    for (int c = 0; c < 12; ++c) d[c] = li[c] * li[c];
    win_acc(d, B[2]);
#pragma unroll
    for (int c = 0; c < 12; ++c) d[c] = lj[c] * lj[c];
    win_acc(d, B[3]);
#pragma unroll
    for (int c = 0; c < 12; ++c) d[c] = li[c] * lj[c];
    win_acc(d, B[4]);
}

// Row-step from LDS ring: add lead (HASL), remove trail (HAST), product-level diff.
template<bool HASL, bool HAST>
__device__ __forceinline__ void upd_lds(const float* __restrict__ Il,
                                        const float* __restrict__ Jl,
                                        const float* __restrict__ It,
                                        const float* __restrict__ Jt,
                                        int t, float B[5][4]) {
    float li[12], lj[12], ti[12], tj[12], d[12];
    if (HASL) { lds12(Il, t, li); lds12(Jl, t, lj); }
    if (HAST) { lds12(It, t, ti); lds12(Jt, t, tj); }

#pragma unroll
    for (int c = 0; c < 12; ++c)
        d[c] = HASL ? (HAST ? li[c] - ti[c] : li[c]) : -ti[c];
    win_acc(d, B[0]);
#pragma unroll
    for (int c = 0; c < 12; ++c)
        d[c] = HASL ? (HAST ? lj[c] - tj[c] : lj[c]) : -tj[c];
    win_acc(d, B[1]);
#pragma unroll
    for (int c = 0; c < 12; ++c)
        d[c] = HASL ? (HAST ? fmaf(li[c], li[c], -(ti[c] * ti[c]))
                            : li[c] * li[c])
                    : -(ti[c] * ti[c]);
    win_acc(d, B[2]);
#pragma unroll
    for (int c = 0; c < 12; ++c)
        d[c] = HASL ? (HAST ? fmaf(lj[c], lj[c], -(tj[c] * tj[c]))
                            : lj[c] * lj[c])
                    : -(tj[c] * tj[c]);
    win_acc(d, B[3]);
#pragma unroll
    for (int c = 0; c < 12; ++c)
        d[c] = HASL ? (HAST ? fmaf(li[c], lj[c], -(ti[c] * tj[c]))
                            : li[c] * lj[c])
                    : -(ti[c] * tj[c]);
    win_acc(d, B[4]);
}

__device__ __forceinline__ float cc_row(const float B[5][4]) {
    const float inv81 = 1.f / 81.f;
    float a = 0.f;
#pragma unroll
    for (int o = 0; o < 4; ++o) {
        float IS = B[0][o], JS = B[1][o];
        float I2 = B[2][o], J2 = B[3][o], IJ = B[4][o];
        float cross = fmaf(-(IS * JS), inv81, IJ);
        float Iv = fmaf(-(IS * IS), inv81, I2);
        float Jv = fmaf(-(JS * JS), inv81, J2);
        float denom = fmaf(Iv, Jv, 1e-5f);
        a = fmaf(cross * cross, __builtin_amdgcn_rcpf(denom), a);
    }
    return a;
}

// 128 threads (2 waves) per block; block owns a 64-row x 512-col strip.
// LDS ring of 16 rows x {I,J}; fills via global_load_lds 4 rows ahead,
// counted vmcnt(6) so loads stay in flight across the barrier.
__global__ __launch_bounds__(128) void ncc_kernel(const float* __restrict__ I,
                                                  const float* __restrict__ J,
                                                  float* __restrict__ ws) {
    __shared__ float ring[2][DRING][WW];        // exactly 64 KB
    const int T  = threadIdx.x;                 // 0..127, owns cols 4T..4T+3
    const int wv = T >> 6;                      // wave 0: cols 0-255, wave 1: 256-511
    const int b  = blockIdx.x >> 3;             // image
    const int r0 = (blockIdx.x & 7) << 6;       // strip base row

    const float* Ib = I + (size_t)b * (HH * WW);
    const float* Jb = J + (size_t)b * (HH * WW);
    const int gcol = T << 2;

    // strip 0: zero-fill slots for rows -4..-1 (slots 12..15)
    if (r0 == 0) {
        const float4 z = make_float4(0.f, 0.f, 0.f, 0.f);
#pragma unroll
        for (int rr = -4; rr < 0; ++rr) {
            reinterpret_cast<float4*>(&ring[0][rr & (DRING - 1)][0])[T] = z;
            reinterpret_cast<float4*>(&ring[1][rr & (DRING - 1)][0])[T] = z;
        }
    }
    // prologue fills: rows r0-4 .. r0+8 (skip negatives; all <= 456, no clamp)
    for (int rr = r0 - 4; rr <= r0 + 8; ++rr) {
        if (rr >= 0) {
            const int sl = rr & (DRING - 1);
            gload16(Ib + (size_t)rr * WW + gcol, &ring[0][sl][wv << 8]);
            gload16(Jb + (size_t)rr * WW + gcol, &ring[1][sl][wv << 8]);
        }
    }
    asm volatile("s_waitcnt vmcnt(0)" ::: "memory");
    __syncthreads();

    float B[5][4];
#pragma unroll
    for (int k = 0; k < 5; ++k)
#pragma unroll
        for (int o = 0; o < 4; ++o) B[k][o] = 0.f;

    // warm-up: fold rows r0-4 .. r0+4 (negative rows read zero-filled slots)
    {
        float vi[12], vj[12];
        for (int j = r0 - 4; j <= r0 + 4; ++j) {
            lds12(&ring[0][j & (DRING - 1)][0], T, vi);
            lds12(&ring[1][j & (DRING - 1)][0], T, vj);
            acc_lead(vi, vj, B);
        }
    }

    float acc = 0.f;
    for (int h = 0; h < RSTRIP; ++h) {
        // rows <= r0+h+5 complete after this wait (3 rows may stay in flight)
        WAITVM(6);
        __builtin_amdgcn_s_barrier();
        {   // issue fill for row r0+h+9 (clamped source; OOB slots never read)
            const int rr = r0 + h + 9;
            const int rc = rr > HH - 1 ? HH - 1 : rr;
            const int sl = rr & (DRING - 1);
            gload16(Ib + (size_t)rc * WW + gcol, &ring[0][sl][wv << 8]);
            gload16(Jb + (size_t)rc * WW + gcol, &ring[1][sl][wv << 8]);
        }
        acc += cc_row(B);                       // output row r0+h
        if (h < RSTRIP - 1) {
            const int jl = r0 + h + 5;          // lead row (in ring)
            const int jt = r0 + h - 4;          // trail row (in ring; <0 = zeros)
            const float* Ilp = &ring[0][jl & (DRING - 1)][0];
            const float* Jlp = &ring[1][jl & (DRING - 1)][0];
            const float* Itp = &ring[0][jt & (DRING - 1)][0];
            const float* Jtp = &ring[1][jt & (DRING - 1)][0];
            if (jl < HH) upd_lds<true, true>(Ilp, Jlp, Itp, Jtp, T, B);
            else         upd_lds<false, true>(Ilp, Jlp, Itp, Jtp, T, B);
        }
    }

    // block reduce (reuse ring LDS; pending fills target slots 5-8, and the
    // __syncthreads drains them anyway)
#pragma unroll
    for (int off = 32; off; off >>= 1) acc += __shfl_down(acc, off);
    __syncthreads();
    if ((T & 63) == 0) ring[0][0][wv] = acc;
    __syncthreads();
    if (T == 0) atomicAdd(&ws[0], ring[0][0][0] + ring[0][0][1]);
}

__global__ __launch_bounds__(256) void reg_kernel(const float* __restrict__ P,
                                                  float* __restrict__ ws) {
    __shared__ float sh[8];
    const int T = threadIdx.x;
    const int c4 = T & 127;                         // 128 float4s = one row
    const int strip = (blockIdx.x << 1) | (T >> 7); // 0..2047 over 65536 rows
    const size_t row0 = (size_t)strip << 5;         // *32 rows per strip
    const bool slast = ((strip & 15) == 15);        // ends at image row 511
    const float* rp = P + row0 * WW + (c4 << 2);

    float sdx = 0.f, sdy = 0.f;
    float4 cur = *reinterpret_cast<const float4*>(rp);
#pragma unroll 8
    for (int i = 0; i < 32; ++i) {
        float d0 = cur.y - cur.x, d1 = cur.z - cur.y, d2 = cur.w - cur.z;
        sdx += d0 * d0 + d1 * d1 + d2 * d2;
        if (c4 < 127) {                             // neighbor elem (cache hit)
            float nx = rp[(size_t)i * WW + 4];
            float d3 = nx - cur.w;
            sdx += d3 * d3;
        }
        if (i < 31) {
            float4 nr = *reinterpret_cast<const float4*>(rp + (size_t)(i + 1) * WW);
            float e0 = nr.x - cur.x, e1 = nr.y - cur.y;
            float e2 = nr.z - cur.z, e3 = nr.w - cur.w;
            sdy += e0 * e0 + e1 * e1 + e2 * e2 + e3 * e3;
            cur = nr;
        } else if (!slast) {
            float4 nr = *reinterpret_cast<const float4*>(rp + (size_t)32 * WW);
            float e0 = nr.x - cur.x, e1 = nr.y - cur.y;
            float e2 = nr.z - cur.z, e3 = nr.w - cur.w;
            sdy += e0 * e0 + e1 * e1 + e2 * e2 + e3 * e3;
        }
    }

#pragma unroll
    for (int off = 32; off; off >>= 1) {
        sdx += __shfl_down(sdx, off);
        sdy += __shfl_down(sdy, off);
    }
    if ((T & 63) == 0) { sh[T >> 6] = sdx; sh[4 + (T >> 6)] = sdy; }
    __syncthreads();
    if (T == 0) {
        atomicAdd(&ws[1], sh[0] + sh[1] + sh[2] + sh[3]);
        atomicAdd(&ws[2], sh[4] + sh[5] + sh[6] + sh[7]);
    }
}

__global__ void finalize_kernel(const float* __restrict__ ws,
                                float* __restrict__ out) {
    float cc_sum = ws[0], dx_sum = ws[1], dy_sum = ws[2];
    float loss_sim = -(cc_sum / 16777216.f);   // 64*512*512
    float mdx = dx_sum / 33488896.f;           // 64*2*512*511
    float mdy = dy_sum / 33488896.f;           // 64*2*511*512
    float loss_reg = (mdx + mdy) * 0.5f * 0.1f;
    out[0] = loss_sim;
    out[1] = loss_reg;
    out[2] = loss_sim + loss_reg;
}

extern "C" void kernel_launch(void* const* d_in, const int* in_sizes, int n_in,
                              void* d_out, int out_size, void* d_ws, size_t ws_size,
                              hipStream_t stream) {
    const float* I = (const float*)d_in[0];   // target_proj
    const float* J = (const float*)d_in[1];   // warped_moving
    const float* P = (const float*)d_in[2];   // phi
    float* out = (float*)d_out;
    float* ws = (float*)d_ws;

    hipMemsetAsync(d_ws, 0, 3 * sizeof(float), stream);
    ncc_kernel<<<512, 128, 0, stream>>>(I, J, ws);        // 2 blocks/CU (64 KB LDS)
    reg_kernel<<<1024, 256, 0, stream>>>(P, ws);          // streaming, full occupancy
    finalize_kernel<<<1, 1, 0, stream>>>(ws, out);
}